// Round 5
// baseline (436.883 us; speedup 1.0000x reference)
//
#include <hip/hip_runtime.h>
#include <hip/hip_bf16.h>

// Problem constants
#define D_DIM   25088
#define B_ROWS  2048
#define C_CLS   100
#define NT      7            // 7 tiles of 16 cols -> 112 padded classes
#define NPAD    112
#define KSTEPS_TOTAL 784     // 25088 / 32
#define EPS     1e-8f

typedef __bf16 bf16x8 __attribute__((ext_vector_type(8)));
typedef float  f32x4  __attribute__((ext_vector_type(4)));
typedef float  f32x2  __attribute__((ext_vector_type(2)));

// RNE float->bf16, pack two into one dword
__device__ __forceinline__ unsigned bfpack2(float lo, float hi) {
    unsigned a = __builtin_bit_cast(unsigned, lo);
    unsigned b = __builtin_bit_cast(unsigned, hi);
    a += 0x7FFFu + ((a >> 16) & 1u);
    b += 0x7FFFu + ((b >> 16) & 1u);
    return (a >> 16) | (b & 0xFFFF0000u);
}

// async global->LDS, 16 bytes per lane; LDS dest must be wave-uniform base
__device__ __forceinline__ void gll16(const uint4* g, uint4* l) {
    __builtin_amdgcn_global_load_lds(
        (const __attribute__((address_space(1))) void*)g,
        (__attribute__((address_space(3))) void*)l, 16, 0, 0);
}

// ---------------- prep: per-class norm partials + pack weight into B-fragment order ----
// Grid (NPAD, 7): block (c, by) handles 7 of the 49 512-float chunks of class row c.
// Norm partial stored PLAIN (no atomics, no zeroing): wnorm2p[by*NPAD + c].
// wpack layout: unit u = gstep*7 + t; lane l = quad*16 + n holds
//   B[k = gstep*32 + quad*8 + j][col = t*16 + n], j=0..7, as 8 bf16 (uint4).
__global__ __launch_bounds__(256) void prep_kernel(const float* __restrict__ w,
                                                   float* __restrict__ wnorm2p,
                                                   unsigned* __restrict__ wpack) {
    int c = blockIdx.x;              // 0..111
    int t = c >> 4, n = c & 15;
    bool real = (c < C_CLS);
    const float* row = w + (size_t)c * D_DIM;
    float s = 0.f;
    int i0 = blockIdx.y * 7;
#pragma unroll
    for (int ii = 0; ii < 7; ++ii) {
        int d = (i0 + ii) * 512 + threadIdx.x * 2;
        f32x2 v = {0.f, 0.f};
        if (real) v = *(const f32x2*)(row + d);
        s += v[0]*v[0] + v[1]*v[1];
        int gstep = d >> 5, r = d & 31, quad = r >> 3, j = r & 7;
        unsigned dw = bfpack2(v[0], v[1]);
        size_t idx = ((size_t)(gstep * 7 + t) * 64 + quad * 16 + n) * 4 + (j >> 1);
        wpack[idx] = dw;
    }
    __shared__ float red[4];
    for (int o = 32; o; o >>= 1) s += __shfl_down(s, o, 64);
    if ((threadIdx.x & 63) == 0) red[threadIdx.x >> 6] = s;
    __syncthreads();
    if (threadIdx.x == 0) wnorm2p[blockIdx.y * NPAD + c] = red[0] + red[1] + red[2] + red[3];
}

// ---------------- main GEMM: dot(f_b, w_c) + sumsq(f_b) ----------------
// 128 rows/block, 32 rows/wave (two 16-row A fragments). Each 7 KB LDS B-tile
// (double-buffered, staged via global_load_lds width-16) now feeds 14 MFMAs
// per wave-step instead of 7 — halving LDS-read and barrier cost per output.
// A register-prefetched one step ahead; KS is a compile-time constant.
template<int KS>
__global__ __launch_bounds__(256, 4) void gemm_kernel(const float* __restrict__ feat,
                                                      const uint4* __restrict__ wpack,
                                                      float* __restrict__ pred2,
                                                      float* __restrict__ fnorm2s) {
    __shared__ uint4 bst[2][NT * 64];   // 2 x 7168 B

    int tid  = threadIdx.x;
    int wave = tid >> 6, lane = tid & 63;
    int m = lane & 15, quad = lane >> 4;
    int rowbase = blockIdx.x * 128 + wave * 32;
    int row0 = rowbase + m;           // fragment 0 rows
    int row1 = rowbase + 16 + m;      // fragment 1 rows
    int sidx = blockIdx.y;
    int gstep0 = sidx * KS;

    const float* pA0 = feat + (size_t)row0 * D_DIM + gstep0 * 32 + quad * 8;
    const float* pA1 = feat + (size_t)row1 * D_DIM + gstep0 * 32 + quad * 8;
    const uint4* qB = wpack + (size_t)gstep0 * NT * 64;

    f32x4 acc0[NT], acc1[NT];
#pragma unroll
    for (int t = 0; t < NT; ++t) {
        acc0[t] = (f32x4){0.f,0.f,0.f,0.f};
        acc1[t] = (f32x4){0.f,0.f,0.f,0.f};
    }
    float ss0 = 0.f, ss1 = 0.f;

    // prologue: stage B[0] into bst[0], load A[0] for both fragments
    gll16(qB + wave * 64 + lane, &bst[0][wave * 64]);
    if (wave < 3) gll16(qB + (wave + 4) * 64 + lane, &bst[0][(wave + 4) * 64]);
    f32x4 a00 = ((const f32x4*)pA0)[0], a01 = ((const f32x4*)pA0)[1];
    f32x4 a10 = ((const f32x4*)pA1)[0], a11 = ((const f32x4*)pA1)[1];
    __syncthreads();

    int cur = 0;
#pragma unroll
    for (int s = 0; s < KS; ++s) {
        // issue next step's B staging + A loads first (land during this step's compute)
        const uint4* qn = qB + NT * 64;
        if (s + 1 < KS) {
            gll16(qn + wave * 64 + lane, &bst[cur ^ 1][wave * 64]);
            if (wave < 3) gll16(qn + (wave + 4) * 64 + lane, &bst[cur ^ 1][(wave + 4) * 64]);
        }
        int adv = (s + 1 < KS) ? 32 : 0;
        f32x4 n00 = ((const f32x4*)(pA0 + adv))[0];
        f32x4 n01 = ((const f32x4*)(pA0 + adv))[1];
        f32x4 n10 = ((const f32x4*)(pA1 + adv))[0];
        f32x4 n11 = ((const f32x4*)(pA1 + adv))[1];

        // compute step s from regs (A) + LDS (B)
        ss0 += a00[0]*a00[0] + a00[1]*a00[1] + a00[2]*a00[2] + a00[3]*a00[3]
             + a01[0]*a01[0] + a01[1]*a01[1] + a01[2]*a01[2] + a01[3]*a01[3];
        ss1 += a10[0]*a10[0] + a10[1]*a10[1] + a10[2]*a10[2] + a10[3]*a10[3]
             + a11[0]*a11[0] + a11[1]*a11[1] + a11[2]*a11[2] + a11[3]*a11[3];
        uint4 ap0, ap1;
        ap0.x = bfpack2(a00[0], a00[1]);
        ap0.y = bfpack2(a00[2], a00[3]);
        ap0.z = bfpack2(a01[0], a01[1]);
        ap0.w = bfpack2(a01[2], a01[3]);
        ap1.x = bfpack2(a10[0], a10[1]);
        ap1.y = bfpack2(a10[2], a10[3]);
        ap1.z = bfpack2(a11[0], a11[1]);
        ap1.w = bfpack2(a11[2], a11[3]);
        bf16x8 af0 = __builtin_bit_cast(bf16x8, ap0);
        bf16x8 af1 = __builtin_bit_cast(bf16x8, ap1);
#pragma unroll
        for (int t = 0; t < NT; ++t) {
            bf16x8 bf = __builtin_bit_cast(bf16x8, bst[cur][t * 64 + lane]);
            acc0[t] = __builtin_amdgcn_mfma_f32_16x16x32_bf16(af0, bf, acc0[t], 0, 0, 0);
            acc1[t] = __builtin_amdgcn_mfma_f32_16x16x32_bf16(af1, bf, acc1[t], 0, 0, 0);
        }

        a00 = n00; a01 = n01; a10 = n10; a11 = n11;
        pA0 += 32; pA1 += 32; qB += NT * 64;
        __syncthreads();
        cur ^= 1;
    }

    // sumsq: reduce across the 4 quads that share row m; lanes 0-15 hold both rows
    ss0 += __shfl_xor(ss0, 16, 64);
    ss0 += __shfl_xor(ss0, 32, 64);
    ss1 += __shfl_xor(ss1, 16, 64);
    ss1 += __shfl_xor(ss1, 32, 64);
    if (lane < 16) {
        fnorm2s[(size_t)sidx * B_ROWS + row0] = ss0;
        fnorm2s[(size_t)sidx * B_ROWS + row1] = ss1;
    }

    // C/D layout (16x16x32 bf16): col = lane&15, row = quad*4 + reg
    float* po = pred2 + ((size_t)sidx * B_ROWS + rowbase) * NPAD;
#pragma unroll
    for (int t = 0; t < NT; ++t) {
#pragma unroll
        for (int r = 0; r < 4; ++r) {
            po[(quad * 4 + r) * NPAD + t * 16 + m]        = acc0[t][r];
            po[(16 + quad * 4 + r) * NPAD + t * 16 + m]   = acc1[t][r];
        }
    }
}

// ---------------- per-row split-reduce + log-softmax / NLL / argmax ----------------
// One wave per row. Sums pred2/fnorm2s over nsplit slabs and wnorm2 over the 7
// prep partials, then writes ONE float4{nll, correct, valid} per row. No atomics.
__global__ __launch_bounds__(256) void finalize_kernel(const float* __restrict__ pred2,
                                                       const float* __restrict__ fnorm2s,
                                                       const float* __restrict__ wnorm2p,
                                                       const void* __restrict__ labp,
                                                       int lab64, int nsplit,
                                                       float4* __restrict__ rowred) {
    int gwave = (blockIdx.x * 256 + threadIdx.x) >> 6;
    int lane = threadIdx.x & 63;
    int row = gwave;
    if (row >= B_ROWS) return;

    // feature norm^2: lane s reads split s's partial, butterfly-sum
    float fn2 = (lane < nsplit) ? fnorm2s[(size_t)lane * B_ROWS + row] : 0.f;
    for (int o = 1; o < 64; o <<= 1) fn2 += __shfl_xor(fn2, o, 64);
    float finv = 10.0f / fmaxf(sqrtf(fn2), EPS);

    // logits: reduce over splits; lane owns cols {lane, lane+64}
    float s0 = 0.f, s1 = 0.f;
    for (int s = 0; s < nsplit; ++s) {
        const float* pr = pred2 + ((size_t)s * B_ROWS + row) * NPAD;
        s0 += pr[lane];
        if (lane < NPAD - 64) s1 += pr[64 + lane];
    }
    int c0 = lane, c1 = lane + 64;
    float wn0 = 0.f, wn1 = 0.f;
#pragma unroll
    for (int j = 0; j < 7; ++j) {
        wn0 += wnorm2p[j * NPAD + c0];
        if (c1 < C_CLS) wn1 += wnorm2p[j * NPAD + c1];
    }
    float l0 = s0 * (1.0f / fmaxf(sqrtf(wn0), EPS)) * finv;  // c0 < 100 always
    float l1 = -1e30f;
    if (c1 < C_CLS) l1 = s1 * (1.0f / fmaxf(sqrtf(wn1), EPS)) * finv;

    // argmax (first-max tie rule: keep smaller index on ties)
    float mx = l0; int am = c0;
    if (l1 > mx) { mx = l1; am = c1; }
    for (int o = 1; o < 64; o <<= 1) {
        float om = __shfl_xor(mx, o, 64);
        int   oa = __shfl_xor(am, o, 64);
        if (om > mx || (om == mx && oa < am)) { mx = om; am = oa; }
    }
    float se = expf(l0 - mx) + expf(l1 - mx);
    for (int o = 1; o < 64; o <<= 1) se += __shfl_xor(se, o, 64);

    int lab = lab64 ? (int)((const long long*)labp)[row] : ((const int*)labp)[row];
    int labc = (lab < 0) ? 0 : lab;
    float lv = (labc >= 64) ? l1 : l0;
    float ll = __shfl(lv, labc & 63, 64);

    if (lane == 0) {
        float lse = mx + logf(se);
        bool valid = (lab >= 0);
        float4 o;
        o.x = valid ? (lse - ll) : 0.f;
        o.y = (valid && am == lab) ? 1.f : 0.f;
        o.z = valid ? 1.f : 0.f;
        o.w = 0.f;
        rowred[row] = o;
    }
}

// ---------------- single-block final reduction: 2048 float4 -> loss, acc ----------------
__global__ __launch_bounds__(256) void reduce_kernel(const float4* __restrict__ rowred,
                                                     float* __restrict__ out) {
    float nll = 0.f, cor = 0.f, val = 0.f;
    for (int i = threadIdx.x; i < B_ROWS; i += 256) {
        float4 v = rowred[i];
        nll += v.x; cor += v.y; val += v.z;
    }
    for (int o = 32; o; o >>= 1) {
        nll += __shfl_down(nll, o, 64);
        cor += __shfl_down(cor, o, 64);
        val += __shfl_down(val, o, 64);
    }
    __shared__ float r[3][4];
    int w = threadIdx.x >> 6;
    if ((threadIdx.x & 63) == 0) { r[0][w] = nll; r[1][w] = cor; r[2][w] = val; }
    __syncthreads();
    if (threadIdx.x == 0) {
        float N = r[0][0] + r[0][1] + r[0][2] + r[0][3];
        float C = r[1][0] + r[1][1] + r[1][2] + r[1][3];
        float V = r[2][0] + r[2][1] + r[2][2] + r[2][3];
        out[0] = N / fmaxf(V, 1.0f);
        out[1] = C / (V + 1e-10f);
    }
}

// Workspace layout (bytes) — nothing needs zeroing (all plain stores):
//   [0, 3136)            wnorm2p         7*112 f32
//   [3328, 36096)        rowred          2048 float4
//   [36352, 5656064)     wpack bf16 B-fragments (784*7*64 uint4)
//   [5656064, 6114816)   fnorm2s         up to 56*2048 f32
//   [6114816, ...)       pred2           nsplit*2048*112 f32
extern "C" void kernel_launch(void* const* d_in, const int* in_sizes, int n_in,
                              void* d_out, int out_size, void* d_ws, size_t ws_size,
                              hipStream_t stream) {
    const float* feat   = (const float*)d_in[0];
    const void*  label  = d_in[1];
    const float* weight = (const float*)d_in[2];
    float* out = (float*)d_out;

    char* ws = (char*)d_ws;
    float*  wnorm2p = (float*)(ws);
    float4* rowred  = (float4*)(ws + 3328);
    uint4*  wpack   = (uint4*)(ws + 36352);
    float*  fnorm2s = (float*)(ws + 5656064);
    float*  pred2   = (float*)(ws + 6114816);

    // choose split count by workspace capacity (ksteps = 784/nsplit)
    int nsplit = 56;
    {
        const int cand[6] = {56, 28, 14, 4, 2, 1};
        for (int i = 0; i < 6; ++i) {
            nsplit = cand[i];
            size_t need = 6114816 + (size_t)nsplit * B_ROWS * NPAD * 4;
            if (need <= ws_size) break;
        }
    }

    int lab64 = (n_in > 1 && in_sizes[1] >= B_ROWS * 8) ? 1 : 0;

    prep_kernel<<<dim3(NPAD, 7), 256, 0, stream>>>(weight, wnorm2p, (unsigned*)wpack);
    dim3 ggrid(B_ROWS / 128, nsplit);
    switch (nsplit) {
        case 56: gemm_kernel<14> <<<ggrid, 256, 0, stream>>>(feat, wpack, pred2, fnorm2s); break;
        case 28: gemm_kernel<28> <<<ggrid, 256, 0, stream>>>(feat, wpack, pred2, fnorm2s); break;
        case 14: gemm_kernel<56> <<<ggrid, 256, 0, stream>>>(feat, wpack, pred2, fnorm2s); break;
        case 4:  gemm_kernel<196><<<ggrid, 256, 0, stream>>>(feat, wpack, pred2, fnorm2s); break;
        case 2:  gemm_kernel<392><<<ggrid, 256, 0, stream>>>(feat, wpack, pred2, fnorm2s); break;
        default: gemm_kernel<784><<<ggrid, 256, 0, stream>>>(feat, wpack, pred2, fnorm2s); break;
    }
    finalize_kernel<<<B_ROWS / 4, 256, 0, stream>>>(pred2, fnorm2s, wnorm2p, label, lab64, nsplit, rowred);
    reduce_kernel<<<1, 256, 0, stream>>>(rowred, out);
}

// Round 6
// 328.945 us; speedup vs baseline: 1.3281x; 1.3281x over previous
//
#include <hip/hip_runtime.h>
#include <hip/hip_bf16.h>

// Problem constants
#define D_DIM   25088
#define B_ROWS  2048
#define C_CLS   100
#define NT      7            // 7 tiles of 16 cols -> 112 padded classes
#define NPAD    112
#define KSTEPS_TOTAL 784     // 25088 / 32
#define EPS     1e-8f

typedef __bf16 bf16x8 __attribute__((ext_vector_type(8)));
typedef float  f32x4  __attribute__((ext_vector_type(4)));
typedef float  f32x2  __attribute__((ext_vector_type(2)));

// RNE float->bf16, pack two into one dword
__device__ __forceinline__ unsigned bfpack2(float lo, float hi) {
    unsigned a = __builtin_bit_cast(unsigned, lo);
    unsigned b = __builtin_bit_cast(unsigned, hi);
    a += 0x7FFFu + ((a >> 16) & 1u);
    b += 0x7FFFu + ((b >> 16) & 1u);
    return (a >> 16) | (b & 0xFFFF0000u);
}

// async global->LDS, 16 bytes per lane; LDS dest must be wave-uniform base
__device__ __forceinline__ void gll16(const uint4* g, uint4* l) {
    __builtin_amdgcn_global_load_lds(
        (const __attribute__((address_space(1))) void*)g,
        (__attribute__((address_space(3))) void*)l, 16, 0, 0);
}

// ---------------- prep: per-class norm partials + pack weight into B-fragment order ----
// Grid (NPAD, 7): block (c, by) handles 7 of the 49 512-float chunks of class row c.
// Norm partial stored PLAIN (no atomics, no zeroing): wnorm2p[by*NPAD + c].
// wpack layout: unit u = gstep*7 + t; lane l = quad*16 + n holds
//   B[k = gstep*32 + quad*8 + j][col = t*16 + n], j=0..7, as 8 bf16 (uint4).
__global__ __launch_bounds__(256) void prep_kernel(const float* __restrict__ w,
                                                   float* __restrict__ wnorm2p,
                                                   unsigned* __restrict__ wpack) {
    int c = blockIdx.x;              // 0..111
    int t = c >> 4, n = c & 15;
    bool real = (c < C_CLS);
    const float* row = w + (size_t)c * D_DIM;
    float s = 0.f;
    int i0 = blockIdx.y * 7;
#pragma unroll
    for (int ii = 0; ii < 7; ++ii) {
        int d = (i0 + ii) * 512 + threadIdx.x * 2;
        f32x2 v = {0.f, 0.f};
        if (real) v = *(const f32x2*)(row + d);
        s += v[0]*v[0] + v[1]*v[1];
        int gstep = d >> 5, r = d & 31, quad = r >> 3, j = r & 7;
        unsigned dw = bfpack2(v[0], v[1]);
        size_t idx = ((size_t)(gstep * 7 + t) * 64 + quad * 16 + n) * 4 + (j >> 1);
        wpack[idx] = dw;
    }
    __shared__ float red[4];
    for (int o = 32; o; o >>= 1) s += __shfl_down(s, o, 64);
    if ((threadIdx.x & 63) == 0) red[threadIdx.x >> 6] = s;
    __syncthreads();
    if (threadIdx.x == 0) wnorm2p[blockIdx.y * NPAD + c] = red[0] + red[1] + red[2] + red[3];
}

// ---------------- main GEMM: dot(f_b, w_c) + sumsq(f_b) ----------------
// 64 rows/block, 16 rows/wave (single A fragment — acc stays at 28 regs, no
// spill; r5's 2-fragment unrolled variant spilled to scratch: VGPR=64 with
// 250 MB of scratch writes). Barrier cost halved instead by staging TWO
// K-steps (BK=64, 14 KB) per LDS stage: 14 MFMAs + 14 ds_read_b128 per
// barrier interval. A register-prefetched one step ahead (16 regs).
// Runtime ksteps arg -> no full unroll -> bounded live set.
__global__ __launch_bounds__(256, 4) void gemm_kernel(const float* __restrict__ feat,
                                                      const uint4* __restrict__ wpack,
                                                      float* __restrict__ pred2,
                                                      float* __restrict__ fnorm2s,
                                                      int ksteps) {
    __shared__ uint4 bst[2][2 * NT * 64];   // 2 x 14336 B (two K-steps per stage)

    int tid  = threadIdx.x;
    int wave = tid >> 6, lane = tid & 63;
    int m = lane & 15, quad = lane >> 4;
    int rowbase = blockIdx.x * 64 + wave * 16;
    int row = rowbase + m;
    int sidx = blockIdx.y;
    int gstep0 = sidx * ksteps;

    const float* pA = feat + (size_t)row * D_DIM + gstep0 * 32 + quad * 8;
    const uint4* qB = wpack + (size_t)gstep0 * NT * 64;   // step-s global B base

    f32x4 acc[NT];
#pragma unroll
    for (int t = 0; t < NT; ++t) acc[t] = (f32x4){0.f,0.f,0.f,0.f};
    float sumsq = 0.f;

    // stage the 14 units (64 uint4 each) of steps {s, s+1} into dstbuf
#define STAGE(dstbuf, src)                                                     \
    do {                                                                       \
        _Pragma("unroll")                                                      \
        for (int k = 0; k < 4; ++k) {                                          \
            int u = wave + 4 * k;                                              \
            if (u < 2 * NT) gll16((src) + u * 64 + lane, &(dstbuf)[u * 64]);   \
        }                                                                      \
    } while (0)

#define STEP(A0, A1, H)                                                        \
    do {                                                                       \
        sumsq += A0[0]*A0[0] + A0[1]*A0[1] + A0[2]*A0[2] + A0[3]*A0[3]         \
               + A1[0]*A1[0] + A1[1]*A1[1] + A1[2]*A1[2] + A1[3]*A1[3];        \
        uint4 ap;                                                              \
        ap.x = bfpack2(A0[0], A0[1]);                                          \
        ap.y = bfpack2(A0[2], A0[3]);                                          \
        ap.z = bfpack2(A1[0], A1[1]);                                          \
        ap.w = bfpack2(A1[2], A1[3]);                                          \
        bf16x8 afrag = __builtin_bit_cast(bf16x8, ap);                         \
        _Pragma("unroll")                                                      \
        for (int t = 0; t < NT; ++t) {                                         \
            bf16x8 bfrag = __builtin_bit_cast(                                 \
                bf16x8, bst[cur][((H) * NT + t) * 64 + lane]);                 \
            acc[t] = __builtin_amdgcn_mfma_f32_16x16x32_bf16(afrag, bfrag,     \
                                                             acc[t], 0, 0, 0);\
        }                                                                      \
    } while (0)

    // prologue: stage steps {0,1}, load step-0 A into regs
    STAGE(bst[0], qB);
    f32x4 a0 = ((const f32x4*)pA)[0], a1 = ((const f32x4*)pA)[1];
    __syncthreads();

    int cur = 0;
    // ksteps is always even (784/nsplit for nsplit in {28,8,4,2,1})
    for (int s = 0; s < ksteps; s += 2) {
        // issue next stage's B staging first (lands at this stage's barrier)
        if (s + 2 < ksteps) STAGE(bst[cur ^ 1], qB + 2 * NT * 64);

        // step s: prefetch A for s+1, compute from LDS half 0
        f32x4 n0 = ((const f32x4*)(pA + 32))[0];
        f32x4 n1 = ((const f32x4*)(pA + 32))[1];
        STEP(a0, a1, 0);

        // step s+1: prefetch A for s+2 (clamped on last stage), compute half 1
        int adv = (s + 2 < ksteps) ? 64 : 32;
        a0 = ((const f32x4*)(pA + adv))[0];
        a1 = ((const f32x4*)(pA + adv))[1];
        STEP(n0, n1, 1);

        pA += 64; qB += 2 * NT * 64;
        __syncthreads();
        cur ^= 1;
    }
#undef STEP
#undef STAGE

    // sumsq: reduce across the 4 quads that share row m; lane<16 holds rows
    sumsq += __shfl_xor(sumsq, 16, 64);
    sumsq += __shfl_xor(sumsq, 32, 64);
    if (lane < 16) fnorm2s[(size_t)sidx * B_ROWS + row] = sumsq;

    // C/D layout (16x16x32 bf16): col = lane&15, row = quad*4 + reg
    float* po = pred2 + ((size_t)sidx * B_ROWS + rowbase) * NPAD;
#pragma unroll
    for (int t = 0; t < NT; ++t) {
#pragma unroll
        for (int r = 0; r < 4; ++r) {
            po[(quad * 4 + r) * NPAD + t * 16 + m] = acc[t][r];
        }
    }
}

// ---------------- per-row split-reduce + log-softmax / NLL / argmax ----------------
// One wave per row. Sums pred2/fnorm2s over nsplit slabs and wnorm2 over the 7
// prep partials, then writes ONE float4{nll, correct, valid} per row. No atomics.
__global__ __launch_bounds__(256) void finalize_kernel(const float* __restrict__ pred2,
                                                       const float* __restrict__ fnorm2s,
                                                       const float* __restrict__ wnorm2p,
                                                       const void* __restrict__ labp,
                                                       int lab64, int nsplit,
                                                       float4* __restrict__ rowred) {
    int gwave = (blockIdx.x * 256 + threadIdx.x) >> 6;
    int lane = threadIdx.x & 63;
    int row = gwave;
    if (row >= B_ROWS) return;

    // feature norm^2: lane s reads split s's partial, butterfly-sum
    float fn2 = (lane < nsplit) ? fnorm2s[(size_t)lane * B_ROWS + row] : 0.f;
    for (int o = 1; o < 64; o <<= 1) fn2 += __shfl_xor(fn2, o, 64);
    float finv = 10.0f / fmaxf(sqrtf(fn2), EPS);

    // logits: reduce over splits; lane owns cols {lane, lane+64}
    float s0 = 0.f, s1 = 0.f;
    for (int s = 0; s < nsplit; ++s) {
        const float* pr = pred2 + ((size_t)s * B_ROWS + row) * NPAD;
        s0 += pr[lane];
        if (lane < NPAD - 64) s1 += pr[64 + lane];
    }
    int c0 = lane, c1 = lane + 64;
    float wn0 = 0.f, wn1 = 0.f;
#pragma unroll
    for (int j = 0; j < 7; ++j) {
        wn0 += wnorm2p[j * NPAD + c0];
        if (c1 < C_CLS) wn1 += wnorm2p[j * NPAD + c1];
    }
    float l0 = s0 * (1.0f / fmaxf(sqrtf(wn0), EPS)) * finv;  // c0 < 100 always
    float l1 = -1e30f;
    if (c1 < C_CLS) l1 = s1 * (1.0f / fmaxf(sqrtf(wn1), EPS)) * finv;

    // argmax (first-max tie rule: keep smaller index on ties)
    float mx = l0; int am = c0;
    if (l1 > mx) { mx = l1; am = c1; }
    for (int o = 1; o < 64; o <<= 1) {
        float om = __shfl_xor(mx, o, 64);
        int   oa = __shfl_xor(am, o, 64);
        if (om > mx || (om == mx && oa < am)) { mx = om; am = oa; }
    }
    float se = expf(l0 - mx) + expf(l1 - mx);
    for (int o = 1; o < 64; o <<= 1) se += __shfl_xor(se, o, 64);

    int lab = lab64 ? (int)((const long long*)labp)[row] : ((const int*)labp)[row];
    int labc = (lab < 0) ? 0 : lab;
    float lv = (labc >= 64) ? l1 : l0;
    float ll = __shfl(lv, labc & 63, 64);

    if (lane == 0) {
        float lse = mx + logf(se);
        bool valid = (lab >= 0);
        float4 o;
        o.x = valid ? (lse - ll) : 0.f;
        o.y = (valid && am == lab) ? 1.f : 0.f;
        o.z = valid ? 1.f : 0.f;
        o.w = 0.f;
        rowred[row] = o;
    }
}

// ---------------- single-block final reduction: 2048 float4 -> loss, acc ----------------
__global__ __launch_bounds__(256) void reduce_kernel(const float4* __restrict__ rowred,
                                                     float* __restrict__ out) {
    float nll = 0.f, cor = 0.f, val = 0.f;
    for (int i = threadIdx.x; i < B_ROWS; i += 256) {
        float4 v = rowred[i];
        nll += v.x; cor += v.y; val += v.z;
    }
    for (int o = 32; o; o >>= 1) {
        nll += __shfl_down(nll, o, 64);
        cor += __shfl_down(cor, o, 64);
        val += __shfl_down(val, o, 64);
    }
    __shared__ float r[3][4];
    int w = threadIdx.x >> 6;
    if ((threadIdx.x & 63) == 0) { r[0][w] = nll; r[1][w] = cor; r[2][w] = val; }
    __syncthreads();
    if (threadIdx.x == 0) {
        float N = r[0][0] + r[0][1] + r[0][2] + r[0][3];
        float C = r[1][0] + r[1][1] + r[1][2] + r[1][3];
        float V = r[2][0] + r[2][1] + r[2][2] + r[2][3];
        out[0] = N / fmaxf(V, 1.0f);
        out[1] = C / (V + 1e-10f);
    }
}

// Workspace layout (bytes) — nothing needs zeroing (all plain stores):
//   [0, 3136)            wnorm2p         7*112 f32
//   [3328, 36096)        rowred          2048 float4
//   [36352, 5656064)     wpack bf16 B-fragments (784*7*64 uint4)
//   [5656064, 5885440)   fnorm2s         up to 28*2048 f32
//   [5885440, ...)       pred2           nsplit*2048*112 f32
extern "C" void kernel_launch(void* const* d_in, const int* in_sizes, int n_in,
                              void* d_out, int out_size, void* d_ws, size_t ws_size,
                              hipStream_t stream) {
    const float* feat   = (const float*)d_in[0];
    const void*  label  = d_in[1];
    const float* weight = (const float*)d_in[2];
    float* out = (float*)d_out;

    char* ws = (char*)d_ws;
    float*  wnorm2p = (float*)(ws);
    float4* rowred  = (float4*)(ws + 3328);
    uint4*  wpack   = (uint4*)(ws + 36352);
    float*  fnorm2s = (float*)(ws + 5656064);
    float*  pred2   = (float*)(ws + 5885440);

    // choose split count by workspace capacity (ksteps = 784/nsplit, always even)
    int nsplit = 28;
    {
        const int cand[5] = {28, 8, 4, 2, 1};
        for (int i = 0; i < 5; ++i) {
            nsplit = cand[i];
            size_t need = 5885440 + (size_t)nsplit * B_ROWS * NPAD * 4;
            if (need <= ws_size) break;
        }
    }
    int ksteps = KSTEPS_TOTAL / nsplit;

    int lab64 = (n_in > 1 && in_sizes[1] >= B_ROWS * 8) ? 1 : 0;

    prep_kernel<<<dim3(NPAD, 7), 256, 0, stream>>>(weight, wnorm2p, (unsigned*)wpack);
    gemm_kernel<<<dim3(B_ROWS / 64, nsplit), 256, 0, stream>>>(feat, wpack, pred2, fnorm2s, ksteps);
    finalize_kernel<<<B_ROWS / 4, 256, 0, stream>>>(pred2, fnorm2s, wnorm2p, label, lab64, nsplit, rowred);
    reduce_kernel<<<1, 256, 0, stream>>>(rowred, out);
}